// Round 1
// baseline (2181.769 us; speedup 1.0000x reference)
//
#include <hip/hip_runtime.h>
#include <hip/hip_fp16.h>
#include <stdint.h>

#define SEQ   1024
#define BATCH 128
#define INDIM 256
#define HID   512
#define INV_TAU 0.1f

typedef _Float16 f16;
typedef _Float16 f16x2 __attribute__((ext_vector_type(2)));
typedef _Float16 f16x8 __attribute__((ext_vector_type(8)));
typedef float    f32x4 __attribute__((ext_vector_type(4)));

static __device__ __forceinline__ f16x2 pk2(float a, float b) {
  auto r = __builtin_amdgcn_cvt_pkrtz(a, b);
  union { decltype(r) i; f16x2 o; } u;
  u.i = r;
  return u.o;
}

// ---------------------------------------------------------------------------
// K1: A = x @ win + bias  -> written into d_out (in place; K2 overwrites with h)
// ---------------------------------------------------------------------------
__global__ __launch_bounds__(512, 2)
void k1_gemm(const float* __restrict__ x, const float* __restrict__ win,
             const float* __restrict__ bias, float* __restrict__ out) {
  __shared__ __align__(16) f16x2 b_lds[HID][20];

  const int tid  = threadIdx.x;
  const int lane = tid & 63;
  const int wid  = tid >> 6;
  const int wr2  = wid >> 2;
  const int wc   = wid & 3;
  const int l15  = lane & 15;
  const int kg   = lane >> 4;

  const long m0 = (long)blockIdx.x * 64;

  f32x4 acc[2][8];
  #pragma unroll
  for (int a = 0; a < 2; ++a)
    #pragma unroll
    for (int bq = 0; bq < 8; ++bq) acc[a][bq] = (f32x4){0.f, 0.f, 0.f, 0.f};

  const int sp0 = (tid >> 8) * 8;
  const int sn0 = tid & 255;

  for (int ks = 0; ks < 8; ++ks) {
    const int k0 = ks * 32;
    #pragma unroll
    for (int r = 0; r < 8; ++r) {
      const int p = sp0 + r;
      #pragma unroll
      for (int i = 0; i < 2; ++i) {
        const int n = sn0 + 256 * i;
        const float lo = win[(k0 + 2 * p) * HID + n];
        const float hi = win[(k0 + 2 * p + 1) * HID + n];
        const int g  = p >> 2;
        const int gs = g ^ (n & 3);
        b_lds[n][gs * 4 + (p & 3)] = pk2(lo, hi);
      }
    }
    __syncthreads();

    f16x8 af[2];
    #pragma unroll
    for (int mf = 0; mf < 2; ++mf) {
      const long row = m0 + wr2 * 32 + mf * 16 + l15;
      const float4* xp = (const float4*)(x + row * INDIM + k0 + kg * 8);
      const float4 a0 = xp[0];
      const float4 a1 = xp[1];
      union { f16x2 h2[4]; f16x8 h8; } u;
      u.h2[0] = pk2(a0.x, a0.y); u.h2[1] = pk2(a0.z, a0.w);
      u.h2[2] = pk2(a1.x, a1.y); u.h2[3] = pk2(a1.z, a1.w);
      af[mf] = u.h8;
    }

    #pragma unroll
    for (int nf = 0; nf < 8; ++nf) {
      const int n  = wc * 128 + nf * 16 + l15;
      const int gs = kg ^ (n & 3);
      union { uint4 v; f16x8 h8; } u;
      u.v = *(const uint4*)&b_lds[n][gs * 4];
      #pragma unroll
      for (int mf = 0; mf < 2; ++mf)
        acc[mf][nf] = __builtin_amdgcn_mfma_f32_16x16x32_f16(af[mf], u.h8, acc[mf][nf], 0, 0, 0);
    }
    __syncthreads();
  }

  #pragma unroll
  for (int nf = 0; nf < 8; ++nf) {
    const int col = wc * 128 + nf * 16 + l15;
    const float bc = bias[col];
    #pragma unroll
    for (int mf = 0; mf < 2; ++mf) {
      const long rowb = m0 + wr2 * 32 + mf * 16 + kg * 4;
      #pragma unroll
      for (int r = 0; r < 4; ++r)
        out[(rowb + r) * HID + col] = acc[mf][nf][r] + bc;
    }
  }
}

// ---------------------------------------------------------------------------
// K2 (new): PAIRED column-split recurrence. 256 blocks x 512 threads -> ALL
// 256 CUs (was 128). Block g: batch b = g&127, half hf = g>>7, owns 256
// output cols [256*hf, 256*hf+256). Partner = g^128 (same XCD mod 8).
//
// Per thread: q = tid&7 (k-slice of 64), jj = tid>>3; 4 cols (jj + 64m),
// weights = 64k x 4cols = 128 f16x2 NAMED registers -> ~175 VGPR total,
// ~80 regs of slack: spill-proof (old kernel: 192 W regs, VGPR_Count=128,
// +40MB scratch writes, ~2700cy/step of L2 reloads).
// Weights are 100%% register-resident -> zero LDS weight traffic.
//
// h exchange per step: self-validating agent-scope mailbox word per column:
//   u32 = (tag=t+1)<<16 | f16(h).  Relaxed AGENT atomics (sc1, LLC-coherent,
// no fences / no L2 writeback ops). Double-buffered slots (t&1); monotone
// tags + the pairwise dependence make overwrite-before-read impossible.
// Readers = threads 256..511 (one word each), spin with s_sleep.
//
// h broadcast in LDS is XOR-swizzled: uint4 index (8q+s)^q -> the 8 q-groups
// of a wave hit 8 distinct 4-bank groups (old layout: 8-way conflict, 9M
// conflict cycles).  One barrier per step.
// ---------------------------------------------------------------------------
#define MBOX_WORDS (2 * 128 * 2 * 256)
#define MBOX_BYTES (MBOX_WORDS * 4)

static __device__ __forceinline__ int hswz(int k) {
  const int w = k >> 1;                       // f16x2 word index 0..255
  const int p = w ^ (((w >> 5) & 7) << 2);    // spread q-groups across banks
  return p * 2 + (k & 1);                     // f16 element index
}

#define DECL_V(u) f16x2 V##u##_0, V##u##_1, V##u##_2, V##u##_3;

#define INIT_V(u) { \
  const float* r0 = wr + (long)(64 * q + 2 * (u)) * HID; \
  const float* r1 = r0 + HID; \
  V##u##_0 = pk2(r0[c0      ], r1[c0      ]); \
  V##u##_1 = pk2(r0[c0 +  64], r1[c0 +  64]); \
  V##u##_2 = pk2(r0[c0 + 128], r1[c0 + 128]); \
  V##u##_3 = pk2(r0[c0 + 192], r1[c0 + 192]); }

#define FMAV(u, i) { const f16x2 hh = hu.h2[i]; \
  a0 = __builtin_elementwise_fma(hh, V##u##_0, a0); \
  a1 = __builtin_elementwise_fma(hh, V##u##_1, a1); \
  a2 = __builtin_elementwise_fma(hh, V##u##_2, a2); \
  a3 = __builtin_elementwise_fma(hh, V##u##_3, a3); }

#define GROUPV(s, u0,u1,u2,u3) { \
  union { uint4 v; f16x2 h2[4]; } hu; \
  hu.v = hb4[(8 * q + (s)) ^ q]; \
  FMAV(u0,0) FMAV(u1,1) FMAV(u2,2) FMAV(u3,3) }

__global__ __launch_bounds__(512, 2)
void k2_pair(const float* __restrict__ wr, float* __restrict__ out,
             uint32_t* __restrict__ mbox) {
  __shared__ __align__(16) uint32_t hbuf[2][256];   // 2KB: double-buffered h (f16, swizzled)

  const int tid = threadIdx.x;
  const int q   = tid & 7;        // k-slice: k in [64q, 64q+64)
  const int jj  = tid >> 3;       // 0..63
  const int b   = blockIdx.x & 127;
  const int hf  = blockIdx.x >> 7;
  const int C0  = hf * 256;
  const int Cp  = C0 ^ 256;
  const int c0  = C0 + jj;        // base col of this thread's 4 cols

  // ---- weights: 128 f16x2 named SSA regs, k in [64q,64q+64) x cols {c0+64m}
  DECL_V(0)  DECL_V(1)  DECL_V(2)  DECL_V(3)  DECL_V(4)  DECL_V(5)
  DECL_V(6)  DECL_V(7)  DECL_V(8)  DECL_V(9)  DECL_V(10) DECL_V(11)
  DECL_V(12) DECL_V(13) DECL_V(14) DECL_V(15) DECL_V(16) DECL_V(17)
  DECL_V(18) DECL_V(19) DECL_V(20) DECL_V(21) DECL_V(22) DECL_V(23)
  DECL_V(24) DECL_V(25) DECL_V(26) DECL_V(27) DECL_V(28) DECL_V(29)
  DECL_V(30) DECL_V(31)

  INIT_V(0)  INIT_V(1)  INIT_V(2)  INIT_V(3)  INIT_V(4)  INIT_V(5)
  INIT_V(6)  INIT_V(7)  INIT_V(8)  INIT_V(9)  INIT_V(10) INIT_V(11)
  INIT_V(12) INIT_V(13) INIT_V(14) INIT_V(15) INIT_V(16) INIT_V(17)
  INIT_V(18) INIT_V(19) INIT_V(20) INIT_V(21) INIT_V(22) INIT_V(23)
  INIT_V(24) INIT_V(25) INIT_V(26) INIT_V(27) INIT_V(28) INIT_V(29)
  INIT_V(30) INIT_V(31)

  if (tid < 256) { hbuf[0][tid] = 0u; hbuf[1][tid] = 0u; }
  __syncthreads();

  // mailbox bases (slot double-buffer by t&1)
  uint32_t*       mb_me0 = mbox + ((hf * 128 + b) * 2 + 0) * 256;
  uint32_t*       mb_me1 = mb_me0 + 256;
  const uint32_t* mb_pt0 = mbox + (((hf ^ 1) * 128 + b) * 2 + 0) * 256;
  const uint32_t* mb_pt1 = mb_pt0 + 256;

  const int col = C0 + jj + 64 * q;           // owner (q<4) output column
  float h  = 0.0f;
  float av = (q < 4) ? out[(long)b * HID + col] : 0.0f;   // A[0] prefetch

  const f16x2 Z2 = {(f16)0.f, (f16)0.f};

  #pragma unroll 1
  for (int t = 0; t < SEQ; ++t) {
    const int nxt = (t & 1) ^ 1;
    const uint4* hb4 = (const uint4*)(&hbuf[t & 1][0]);

    f16x2 a0 = Z2, a1 = Z2, a2 = Z2, a3 = Z2;
    GROUPV(0,  0, 1, 2, 3)   GROUPV(1,  4, 5, 6, 7)
    GROUPV(2,  8, 9,10,11)   GROUPV(3, 12,13,14,15)
    GROUPV(4, 16,17,18,19)   GROUPV(5, 20,21,22,23)
    GROUPV(6, 24,25,26,27)   GROUPV(7, 28,29,30,31)

    // reduce the 8 k-slices (octet: lanes differ in bits 0..2)
    float y0 = (float)a0[0] + (float)a0[1];
    float y1 = (float)a1[0] + (float)a1[1];
    float y2 = (float)a2[0] + (float)a2[1];
    float y3 = (float)a3[0] + (float)a3[1];
    y0 += __shfl_xor(y0, 1); y0 += __shfl_xor(y0, 2); y0 += __shfl_xor(y0, 4);
    y1 += __shfl_xor(y1, 1); y1 += __shfl_xor(y1, 2); y1 += __shfl_xor(y1, 4);
    y2 += __shfl_xor(y2, 1); y2 += __shfl_xor(y2, 2); y2 += __shfl_xor(y2, 4);
    y3 += __shfl_xor(y3, 1); y3 += __shfl_xor(y3, 2); y3 += __shfl_xor(y3, 4);

    if (q < 4) {
      const float y   = (q == 0) ? y0 : (q == 1) ? y1 : (q == 2) ? y2 : y3;
      const float arg = av + y;
      const float e   = __expf(2.0f * arg);
      const float th  = 1.0f - 2.0f / (e + 1.0f);
      h += INV_TAU * (th - h);
      const f16 hf16 = (f16)h;

      // publish FIRST (partner is waiting on it)
      if (t + 1 < SEQ) {
        union { unsigned short u; f16 v; } cv; cv.v = hf16;
        const uint32_t word = ((uint32_t)(t + 1) << 16) | (uint32_t)cv.u;
        uint32_t* mb_me = (t & 1) ? mb_me1 : mb_me0;
        __hip_atomic_store(mb_me + (jj + 64 * q), word,
                           __ATOMIC_RELAXED, __HIP_MEMORY_SCOPE_AGENT);
      }
      const long aofs = ((long)t * BATCH + b) * HID;
      out[aofs + col] = h;
      ((f16*)hbuf[nxt])[hswz(col)] = hf16;            // own half
      const int tn = (t + 1 < SEQ) ? (t + 1) : (SEQ - 1);
      av = out[((long)tn * BATCH + b) * HID + col];   // A[t+1] prefetch
    }

    // readers: waves 4-7, one partner word each; spin on self-validating tag
    if (t + 1 < SEQ && tid >= 256) {
      const int c = tid - 256;
      const uint32_t want = (uint32_t)(t + 1);
      const uint32_t* wp = ((t & 1) ? mb_pt1 : mb_pt0) + c;
      uint32_t v = __hip_atomic_load(wp, __ATOMIC_RELAXED, __HIP_MEMORY_SCOPE_AGENT);
      while ((v >> 16) != want) {
        __builtin_amdgcn_s_sleep(1);
        v = __hip_atomic_load(wp, __ATOMIC_RELAXED, __HIP_MEMORY_SCOPE_AGENT);
      }
      union { unsigned short u; f16 v; } cv; cv.u = (unsigned short)(v & 0xffffu);
      ((f16*)hbuf[nxt])[hswz(Cp + c)] = cv.v;         // partner half
    }
    __syncthreads();    // hbuf[nxt] (both halves) visible for next step
  }
}

// ---------------------------------------------------------------------------
// K2 fallback (previous kernel, used only if workspace is too small)
// ---------------------------------------------------------------------------
#define K2_SMEM (131072 + 16384 + 2048)

#define DECL_W(u) f16x2 W##u##_0, W##u##_1, W##u##_2, W##u##_3;

#define INIT_U(u) { \
    _Pragma("unroll") \
    for (int r = 0; r < 8; ++r) { \
      const int k = (r >> 1) * 96 + 2 * (u) + (r & 1); \
      slab[r][tid] = wr[k * HID + tid]; \
    } \
    __syncthreads(); \
    W##u##_0 = pk2(slab[2*q][jj      ], slab[2*q+1][jj      ]); \
    W##u##_1 = pk2(slab[2*q][jj + 128], slab[2*q+1][jj + 128]); \
    W##u##_2 = pk2(slab[2*q][jj + 256], slab[2*q+1][jj + 256]); \
    W##u##_3 = pk2(slab[2*q][jj + 384], slab[2*q+1][jj + 384]); \
    __syncthreads(); }

#define FMA_U(u, i) { const f16x2 hh_##u = hu.h2[i]; \
    a0 = __builtin_elementwise_fma(hh_##u, W##u##_0, a0); \
    a1 = __builtin_elementwise_fma(hh_##u, W##u##_1, a1); \
    a2 = __builtin_elementwise_fma(hh_##u, W##u##_2, a2); \
    a3 = __builtin_elementwise_fma(hh_##u, W##u##_3, a3); }

#define GROUP(U, u0,u1,u2,u3) { \
    union { uint4 v; f16x2 h2[4]; } hu; \
    hu.v = *(const uint4*)&hb[q * 48 + (U) * 4]; \
    FMA_U(u0,0) FMA_U(u1,1) FMA_U(u2,2) FMA_U(u3,3) }

__global__ __launch_bounds__(512, 2)
void k2_rnn(const float* __restrict__ wr, float* __restrict__ out) {
  extern __shared__ char smem[];
  f16x2 (*w_lds)[64] = (f16x2(*)[64])smem;
  float (*slab)[HID] = (float(*)[HID])(smem + 131072);
  f16x2 (*hbuf)[256] = (f16x2(*)[256])(smem + 131072 + 16384);

  const int tid = threadIdx.x;
  const int q   = tid & 3;
  const int jj  = tid >> 2;
  const int b   = blockIdx.x;

  DECL_W(0)  DECL_W(1)  DECL_W(2)  DECL_W(3)  DECL_W(4)  DECL_W(5)
  DECL_W(6)  DECL_W(7)  DECL_W(8)  DECL_W(9)  DECL_W(10) DECL_W(11)
  DECL_W(12) DECL_W(13) DECL_W(14) DECL_W(15) DECL_W(16) DECL_W(17)
  DECL_W(18) DECL_W(19) DECL_W(20) DECL_W(21) DECL_W(22) DECL_W(23)
  DECL_W(24) DECL_W(25) DECL_W(26) DECL_W(27) DECL_W(28) DECL_W(29)
  DECL_W(30) DECL_W(31) DECL_W(32) DECL_W(33) DECL_W(34) DECL_W(35)
  DECL_W(36) DECL_W(37) DECL_W(38) DECL_W(39) DECL_W(40) DECL_W(41)
  DECL_W(42) DECL_W(43) DECL_W(44) DECL_W(45) DECL_W(46) DECL_W(47)

  INIT_U(0)  INIT_U(1)  INIT_U(2)  INIT_U(3)  INIT_U(4)  INIT_U(5)
  INIT_U(6)  INIT_U(7)  INIT_U(8)  INIT_U(9)  INIT_U(10) INIT_U(11)
  INIT_U(12) INIT_U(13) INIT_U(14) INIT_U(15) INIT_U(16) INIT_U(17)
  INIT_U(18) INIT_U(19) INIT_U(20) INIT_U(21) INIT_U(22) INIT_U(23)
  INIT_U(24) INIT_U(25) INIT_U(26) INIT_U(27) INIT_U(28) INIT_U(29)
  INIT_U(30) INIT_U(31) INIT_U(32) INIT_U(33) INIT_U(34) INIT_U(35)
  INIT_U(36) INIT_U(37) INIT_U(38) INIT_U(39) INIT_U(40) INIT_U(41)
  INIT_U(42) INIT_U(43) INIT_U(44) INIT_U(45) INIT_U(46) INIT_U(47)

  for (int v = 0; v < 16; ++v) {
    #pragma unroll
    for (int r = 0; r < 8; ++r) {
      const int k = 384 + 8 * v + r;
      slab[r][tid] = wr[k * HID + tid];
    }
    __syncthreads();
    const int gs = v ^ (tid & 15);
    #pragma unroll
    for (int pi = 0; pi < 4; ++pi)
      w_lds[tid][gs * 4 + pi] = pk2(slab[2 * pi][tid], slab[2 * pi + 1][tid]);
    __syncthreads();
  }

  const f16x2 Z2 = {(f16)0.f, (f16)0.f};
  if (tid < 256) { hbuf[0][tid] = Z2; hbuf[1][tid] = Z2; }
  __syncthreads();

  const int j = jj + 128 * q;
  const int jlow = jj & 15;
  float h = 0.0f;

  float av = out[(long)b * HID + j];

  #pragma unroll 1
  for (int t = 0; t < SEQ; ++t) {
    const int cur = t & 1;
    const int nxt = cur ^ 1;
    const long aofs = ((long)t * BATCH + b) * HID;
    const int tn = (t + 1 < SEQ) ? (t + 1) : (SEQ - 1);
    const float av_next = out[((long)tn * BATCH + b) * HID + j];

    const f16x2* hb = hbuf[cur];
    f16x2 a0 = Z2, a1 = Z2, a2 = Z2, a3 = Z2;

    GROUP(0,  0, 1, 2, 3)   GROUP(1,  4, 5, 6, 7)
    GROUP(2,  8, 9,10,11)   GROUP(3, 12,13,14,15)
    GROUP(4, 16,17,18,19)   GROUP(5, 20,21,22,23)
    GROUP(6, 24,25,26,27)   GROUP(7, 28,29,30,31)
    GROUP(8, 32,33,34,35)   GROUP(9, 36,37,38,39)
    GROUP(10,40,41,42,43)   GROUP(11,44,45,46,47)

    #pragma unroll
    for (int gi = 0; gi < 4; ++gi) {
      union { uint4 v; f16x2 h2[4]; } hu;
      hu.v = *(const uint4*)&hb[192 + q * 16 + gi * 4];
      const int gsr = ((4 * q + gi) ^ jlow) * 4;
      union { uint4 v; f16x2 h2[4]; } w0, w1, w2, w3;
      w0.v = *(const uint4*)&w_lds[jj      ][gsr];
      w1.v = *(const uint4*)&w_lds[jj + 128][gsr];
      w2.v = *(const uint4*)&w_lds[jj + 256][gsr];
      w3.v = *(const uint4*)&w_lds[jj + 384][gsr];
      #pragma unroll
      for (int i = 0; i < 4; ++i) {
        const f16x2 hh = hu.h2[i];
        a0 = __builtin_elementwise_fma(hh, w0.h2[i], a0);
        a1 = __builtin_elementwise_fma(hh, w1.h2[i], a1);
        a2 = __builtin_elementwise_fma(hh, w2.h2[i], a2);
        a3 = __builtin_elementwise_fma(hh, w3.h2[i], a3);
      }
    }

    float y0 = (float)a0[0] + (float)a0[1];
    float y1 = (float)a1[0] + (float)a1[1];
    float y2 = (float)a2[0] + (float)a2[1];
    float y3 = (float)a3[0] + (float)a3[1];
    y0 += __shfl_xor(y0, 1); y0 += __shfl_xor(y0, 2);
    y1 += __shfl_xor(y1, 1); y1 += __shfl_xor(y1, 2);
    y2 += __shfl_xor(y2, 1); y2 += __shfl_xor(y2, 2);
    y3 += __shfl_xor(y3, 1); y3 += __shfl_xor(y3, 2);
    const float y = (q == 0) ? y0 : (q == 1) ? y1 : (q == 2) ? y2 : y3;

    const float arg = av + y;
    const float e  = __expf(2.0f * arg);
    const float th = 1.0f - 2.0f / (e + 1.0f);
    h += INV_TAU * (th - h);

    out[aofs + j] = h;
    ((f16*)hbuf[nxt])[j] = (f16)h;
    av = av_next;
    __syncthreads();
  }
}

// ---------------------------------------------------------------------------
extern "C" void kernel_launch(void* const* d_in, const int* in_sizes, int n_in,
                              void* d_out, int out_size, void* d_ws, size_t ws_size,
                              hipStream_t stream) {
  const float* x    = (const float*)d_in[0];
  const float* win  = (const float*)d_in[1];
  const float* wr   = (const float*)d_in[2];
  const float* bias = (const float*)d_in[3];
  float* out = (float*)d_out;

  (void)in_sizes; (void)n_in; (void)out_size;

  k1_gemm<<<dim3((SEQ * BATCH) / 64), dim3(512), 0, stream>>>(x, win, bias, out);

  if (d_ws != nullptr && ws_size >= (size_t)MBOX_BYTES) {
    // mailbox tags must start at 0 every launch/replay
    (void)hipMemsetAsync(d_ws, 0, MBOX_BYTES, stream);
    k2_pair<<<dim3(256), dim3(512), 0, stream>>>(wr, out, (uint32_t*)d_ws);
  } else {
    (void)hipFuncSetAttribute((const void*)k2_rnn,
                              hipFuncAttributeMaxDynamicSharedMemorySize, K2_SMEM);
    k2_rnn<<<dim3(BATCH), dim3(512), K2_SMEM, stream>>>(wr, out);
  }
}

// Round 2
// 1891.735 us; speedup vs baseline: 1.1533x; 1.1533x over previous
//
#include <hip/hip_runtime.h>
#include <hip/hip_fp16.h>
#include <stdint.h>

#define SEQ   1024
#define BATCH 128
#define INDIM 256
#define HID   512
#define INV_TAU 0.1f

typedef _Float16 f16;
typedef _Float16 f16x2 __attribute__((ext_vector_type(2)));
typedef _Float16 f16x8 __attribute__((ext_vector_type(8)));
typedef float    f32x4 __attribute__((ext_vector_type(4)));

static __device__ __forceinline__ f16x2 pk2(float a, float b) {
  auto r = __builtin_amdgcn_cvt_pkrtz(a, b);
  union { decltype(r) i; f16x2 o; } u;
  u.i = r;
  return u.o;
}

// ---------------------------------------------------------------------------
// K1: A = x @ win + bias  -> written into d_out (in place; K2 overwrites with h)
// ---------------------------------------------------------------------------
__global__ __launch_bounds__(512, 2)
void k1_gemm(const float* __restrict__ x, const float* __restrict__ win,
             const float* __restrict__ bias, float* __restrict__ out) {
  __shared__ __align__(16) f16x2 b_lds[HID][20];

  const int tid  = threadIdx.x;
  const int lane = tid & 63;
  const int wid  = tid >> 6;
  const int wr2  = wid >> 2;
  const int wc   = wid & 3;
  const int l15  = lane & 15;
  const int kg   = lane >> 4;

  const long m0 = (long)blockIdx.x * 64;

  f32x4 acc[2][8];
  #pragma unroll
  for (int a = 0; a < 2; ++a)
    #pragma unroll
    for (int bq = 0; bq < 8; ++bq) acc[a][bq] = (f32x4){0.f, 0.f, 0.f, 0.f};

  const int sp0 = (tid >> 8) * 8;
  const int sn0 = tid & 255;

  for (int ks = 0; ks < 8; ++ks) {
    const int k0 = ks * 32;
    #pragma unroll
    for (int r = 0; r < 8; ++r) {
      const int p = sp0 + r;
      #pragma unroll
      for (int i = 0; i < 2; ++i) {
        const int n = sn0 + 256 * i;
        const float lo = win[(k0 + 2 * p) * HID + n];
        const float hi = win[(k0 + 2 * p + 1) * HID + n];
        const int g  = p >> 2;
        const int gs = g ^ (n & 3);
        b_lds[n][gs * 4 + (p & 3)] = pk2(lo, hi);
      }
    }
    __syncthreads();

    f16x8 af[2];
    #pragma unroll
    for (int mf = 0; mf < 2; ++mf) {
      const long row = m0 + wr2 * 32 + mf * 16 + l15;
      const float4* xp = (const float4*)(x + row * INDIM + k0 + kg * 8);
      const float4 a0 = xp[0];
      const float4 a1 = xp[1];
      union { f16x2 h2[4]; f16x8 h8; } u;
      u.h2[0] = pk2(a0.x, a0.y); u.h2[1] = pk2(a0.z, a0.w);
      u.h2[2] = pk2(a1.x, a1.y); u.h2[3] = pk2(a1.z, a1.w);
      af[mf] = u.h8;
    }

    #pragma unroll
    for (int nf = 0; nf < 8; ++nf) {
      const int n  = wc * 128 + nf * 16 + l15;
      const int gs = kg ^ (n & 3);
      union { uint4 v; f16x8 h8; } u;
      u.v = *(const uint4*)&b_lds[n][gs * 4];
      #pragma unroll
      for (int mf = 0; mf < 2; ++mf)
        acc[mf][nf] = __builtin_amdgcn_mfma_f32_16x16x32_f16(af[mf], u.h8, acc[mf][nf], 0, 0, 0);
    }
    __syncthreads();
  }

  #pragma unroll
  for (int nf = 0; nf < 8; ++nf) {
    const int col = wc * 128 + nf * 16 + l15;
    const float bc = bias[col];
    #pragma unroll
    for (int mf = 0; mf < 2; ++mf) {
      const long rowb = m0 + wr2 * 32 + mf * 16 + kg * 4;
      #pragma unroll
      for (int r = 0; r < 4; ++r)
        out[(rowb + r) * HID + col] = acc[mf][nf][r] + bc;
    }
  }
}

// ---------------------------------------------------------------------------
// K2: per-batch-row recurrence. 128 blocks x 512 threads, 1 block/CU.
//
// *** __launch_bounds__(512, 1) is load-bearing. ***  With (512, 2) hipcc
// capped the kernel at 128 VGPRs (2nd arg treated as min BLOCKS/CU -> 4
// waves/SIMD -> 2048/4 = 128) and spilled ~110 of the 192 named weight regs
// to scratch; the per-step scratch reloads were ~2700 cy/step (round-0:
// VGPR_Count=128, +40MB WRITE_SIZE, VALUBusy 30%).  (512, 1) -> 1 block/CU
// -> 2 waves/SIMD -> 256-VGPR budget; 192 W regs + ~50 working set fit.
//
// Weights k in [0,384) live in 192 NAMED f16x2 registers per thread
// (W0..W47 x4 cols).  Weights k in [384,512) live in a 128KB LDS cache with
// PLANE-MAJOR layout w4[(gi*4+m)*512 + tid]: each thread reads back exactly
// the uint4 it wrote (no cross-thread sharing, no barrier needed), and each
// static ds_read_b128 is lane-consecutive (base + lane*16) -> zero bank
// conflicts.  (Old layout w_lds[col][swz]: 256B row stride === 0 mod 32
// banks -> bank depended on the column swizzle only -> 8-way conflict on
// all 16 reads/step = the 9M SQ_LDS_BANK_CONFLICT cycles in round 0.)
//
// h f16 pairs double-buffered in LDS, broadcast reads (4 distinct addrs/wave
// = free).  1 barrier per step.  thread: q=tid&3 (k-slice), jj=tid>>2.
// ---------------------------------------------------------------------------
#define K2_SMEM (131072 + 16384 + 2048)

#define DECL_W(u) f16x2 W##u##_0, W##u##_1, W##u##_2, W##u##_3;

#define INIT_U(u) { \
    _Pragma("unroll") \
    for (int r = 0; r < 8; ++r) { \
      const int k = (r >> 1) * 96 + 2 * (u) + (r & 1); \
      slab[r][tid] = wr[k * HID + tid]; \
    } \
    __syncthreads(); \
    W##u##_0 = pk2(slab[2*q][jj      ], slab[2*q+1][jj      ]); \
    W##u##_1 = pk2(slab[2*q][jj + 128], slab[2*q+1][jj + 128]); \
    W##u##_2 = pk2(slab[2*q][jj + 256], slab[2*q+1][jj + 256]); \
    W##u##_3 = pk2(slab[2*q][jj + 384], slab[2*q+1][jj + 384]); \
    __syncthreads(); }

#define FMA_U(u, i) { const f16x2 hh_##u = hu.h2[i]; \
    a0 = __builtin_elementwise_fma(hh_##u, W##u##_0, a0); \
    a1 = __builtin_elementwise_fma(hh_##u, W##u##_1, a1); \
    a2 = __builtin_elementwise_fma(hh_##u, W##u##_2, a2); \
    a3 = __builtin_elementwise_fma(hh_##u, W##u##_3, a3); }

#define GROUP(U, u0,u1,u2,u3) { \
    union { uint4 v; f16x2 h2[4]; } hu; \
    hu.v = *(const uint4*)&hb[q * 48 + (U) * 4]; \
    FMA_U(u0,0) FMA_U(u1,1) FMA_U(u2,2) FMA_U(u3,3) }

__global__ __launch_bounds__(512, 1)
void k2_rnn(const float* __restrict__ wr, float* __restrict__ out) {
  extern __shared__ char smem[];
  uint4* w4          = (uint4*)smem;                               // 8192 uint4 = 128KB
  float (*slab)[HID] = (float(*)[HID])(smem + 131072);             // 8 x 512 fp32 = 16KB
  f16x2 (*hbuf)[256] = (f16x2(*)[256])(smem + 131072 + 16384);     // 2 x 256 pairs = 2KB

  const int tid = threadIdx.x;
  const int q   = tid & 3;
  const int jj  = tid >> 2;
  const int b   = blockIdx.x;

  DECL_W(0)  DECL_W(1)  DECL_W(2)  DECL_W(3)  DECL_W(4)  DECL_W(5)
  DECL_W(6)  DECL_W(7)  DECL_W(8)  DECL_W(9)  DECL_W(10) DECL_W(11)
  DECL_W(12) DECL_W(13) DECL_W(14) DECL_W(15) DECL_W(16) DECL_W(17)
  DECL_W(18) DECL_W(19) DECL_W(20) DECL_W(21) DECL_W(22) DECL_W(23)
  DECL_W(24) DECL_W(25) DECL_W(26) DECL_W(27) DECL_W(28) DECL_W(29)
  DECL_W(30) DECL_W(31) DECL_W(32) DECL_W(33) DECL_W(34) DECL_W(35)
  DECL_W(36) DECL_W(37) DECL_W(38) DECL_W(39) DECL_W(40) DECL_W(41)
  DECL_W(42) DECL_W(43) DECL_W(44) DECL_W(45) DECL_W(46) DECL_W(47)

  // ---- LDS weight cache, k in [384,512): plane-major, self-owned slots.
  // w4[(gi*4+m)*512 + tid] = 4 k-pairs (k = 384+32q+8gi .. +8) of column
  // jj + 128m.  Thread reads back its own slots -> no barrier, no conflicts.
  #pragma unroll
  for (int gi = 0; gi < 4; ++gi) {
    #pragma unroll
    for (int m = 0; m < 4; ++m) {
      const int col = jj + 128 * m;
      const int kb  = 384 + 32 * q + 8 * gi;
      union { uint4 v; f16x2 h2[4]; } u;
      #pragma unroll
      for (int i = 0; i < 4; ++i)
        u.h2[i] = pk2(wr[(long)(kb + 2 * i) * HID + col],
                      wr[(long)(kb + 2 * i + 1) * HID + col]);
      w4[(gi * 4 + m) * 512 + tid] = u.v;
    }
  }

  INIT_U(0)  INIT_U(1)  INIT_U(2)  INIT_U(3)  INIT_U(4)  INIT_U(5)
  INIT_U(6)  INIT_U(7)  INIT_U(8)  INIT_U(9)  INIT_U(10) INIT_U(11)
  INIT_U(12) INIT_U(13) INIT_U(14) INIT_U(15) INIT_U(16) INIT_U(17)
  INIT_U(18) INIT_U(19) INIT_U(20) INIT_U(21) INIT_U(22) INIT_U(23)
  INIT_U(24) INIT_U(25) INIT_U(26) INIT_U(27) INIT_U(28) INIT_U(29)
  INIT_U(30) INIT_U(31) INIT_U(32) INIT_U(33) INIT_U(34) INIT_U(35)
  INIT_U(36) INIT_U(37) INIT_U(38) INIT_U(39) INIT_U(40) INIT_U(41)
  INIT_U(42) INIT_U(43) INIT_U(44) INIT_U(45) INIT_U(46) INIT_U(47)

  const f16x2 Z2 = {(f16)0.f, (f16)0.f};
  if (tid < 256) { hbuf[0][tid] = Z2; hbuf[1][tid] = Z2; }
  __syncthreads();

  const int j = jj + 128 * q;
  float h = 0.0f;

  float av = out[(long)b * HID + j];   // A[0] prefetch

  const uint4* w4t = w4 + tid;

  #pragma unroll 1
  for (int t = 0; t < SEQ; ++t) {
    const int cur = t & 1;
    const int nxt = cur ^ 1;
    const long aofs = ((long)t * BATCH + b) * HID;
    const int tn = (t + 1 < SEQ) ? (t + 1) : (SEQ - 1);
    const float av_next = out[((long)tn * BATCH + b) * HID + j];

    const f16x2* hb = hbuf[cur];
    f16x2 a0 = Z2, a1 = Z2, a2 = Z2, a3 = Z2;

    // register-weight part: k in [96q, 96q+96), straight-line
    GROUP(0,  0, 1, 2, 3)   GROUP(1,  4, 5, 6, 7)
    GROUP(2,  8, 9,10,11)   GROUP(3, 12,13,14,15)
    GROUP(4, 16,17,18,19)   GROUP(5, 20,21,22,23)
    GROUP(6, 24,25,26,27)   GROUP(7, 28,29,30,31)
    GROUP(8, 32,33,34,35)   GROUP(9, 36,37,38,39)
    GROUP(10,40,41,42,43)   GROUP(11,44,45,46,47)

    // LDS-weight part: k in [384+32q, 384+32q+32), conflict-free self-reads
    #pragma unroll
    for (int gi = 0; gi < 4; ++gi) {
      union { uint4 v; f16x2 h2[4]; } hu;
      hu.v = *(const uint4*)&hb[192 + q * 16 + gi * 4];
      union { uint4 v; f16x2 h2[4]; } w0, w1, w2, w3;
      w0.v = w4t[(gi * 4 + 0) * 512];
      w1.v = w4t[(gi * 4 + 1) * 512];
      w2.v = w4t[(gi * 4 + 2) * 512];
      w3.v = w4t[(gi * 4 + 3) * 512];
      #pragma unroll
      for (int i = 0; i < 4; ++i) {
        const f16x2 hh = hu.h2[i];
        a0 = __builtin_elementwise_fma(hh, w0.h2[i], a0);
        a1 = __builtin_elementwise_fma(hh, w1.h2[i], a1);
        a2 = __builtin_elementwise_fma(hh, w2.h2[i], a2);
        a3 = __builtin_elementwise_fma(hh, w3.h2[i], a3);
      }
    }

    // reduce the 4 k-slices
    float y0 = (float)a0[0] + (float)a0[1];
    float y1 = (float)a1[0] + (float)a1[1];
    float y2 = (float)a2[0] + (float)a2[1];
    float y3 = (float)a3[0] + (float)a3[1];
    y0 += __shfl_xor(y0, 1); y0 += __shfl_xor(y0, 2);
    y1 += __shfl_xor(y1, 1); y1 += __shfl_xor(y1, 2);
    y2 += __shfl_xor(y2, 1); y2 += __shfl_xor(y2, 2);
    y3 += __shfl_xor(y3, 1); y3 += __shfl_xor(y3, 2);
    const float y = (q == 0) ? y0 : (q == 1) ? y1 : (q == 2) ? y2 : y3;

    // leaky update: h += 0.1*(tanh(A + y) - h)
    const float arg = av + y;
    const float e  = __expf(2.0f * arg);
    const float th = 1.0f - 2.0f / (e + 1.0f);
    h += INV_TAU * (th - h);

    out[aofs + j] = h;
    ((f16*)hbuf[nxt])[j] = (f16)h;
    av = av_next;
    __syncthreads();
  }
}

// ---------------------------------------------------------------------------
extern "C" void kernel_launch(void* const* d_in, const int* in_sizes, int n_in,
                              void* d_out, int out_size, void* d_ws, size_t ws_size,
                              hipStream_t stream) {
  const float* x    = (const float*)d_in[0];
  const float* win  = (const float*)d_in[1];
  const float* wr   = (const float*)d_in[2];
  const float* bias = (const float*)d_in[3];
  float* out = (float*)d_out;

  (void)d_ws; (void)ws_size; (void)in_sizes; (void)n_in; (void)out_size;

  (void)hipFuncSetAttribute((const void*)k2_rnn,
                            hipFuncAttributeMaxDynamicSharedMemorySize, K2_SMEM);

  k1_gemm<<<dim3((SEQ * BATCH) / 64), dim3(512), 0, stream>>>(x, win, bias, out);
  k2_rnn<<<dim3(BATCH), dim3(512), K2_SMEM, stream>>>(wr, out);
}